// Round 1
// baseline (1228.570 us; speedup 1.0000x reference)
//
#include <hip/hip_runtime.h>

// Problem constants: B=2, S=2048, D_IN=D_OUT=4096, H=32, G=8, HD=128, GS=4
// All matmuls are C[M,N] = A[M,K] @ B[N,K]^T ("gemm_bt", K contiguous in both).

typedef float f32x4 __attribute__((ext_vector_type(4)));
typedef short s16x8 __attribute__((ext_vector_type(8)));

__device__ __forceinline__ unsigned short f32_to_bf16(float f) {
    unsigned int u = __float_as_uint(f);
    u += 0x7fffu + ((u >> 16) & 1u);   // round-to-nearest-even
    return (unsigned short)(u >> 16);
}
__device__ __forceinline__ float bf16_to_f32(unsigned short h) {
    return __uint_as_float(((unsigned int)h) << 16);
}
// async global->LDS, 16B per lane. LDS dest is wave-uniform base + lane*16.
__device__ __forceinline__ void async16(const unsigned short* g, unsigned short* l) {
    __builtin_amdgcn_global_load_lds(
        (const __attribute__((address_space(1))) unsigned int*)g,
        (__attribute__((address_space(3))) unsigned int*)l, 16, 0, 0);
}

// ---------------- fp32 -> bf16 cast ----------------
__global__ __launch_bounds__(256) void cast_f32_bf16(
    const float* __restrict__ in, unsigned short* __restrict__ out, int n4)
{
    int idx = blockIdx.x * 256 + threadIdx.x;
    if (idx >= n4) return;
    float4 v = ((const float4*)in)[idx];
    ushort4 o;
    o.x = f32_to_bf16(v.x); o.y = f32_to_bf16(v.y);
    o.z = f32_to_bf16(v.z); o.w = f32_to_bf16(v.w);
    ((ushort4*)out)[idx] = o;
}

// ---------------- bf16 gemm_bt: C = A[M,K] * B[N,K]^T ----------------
// 128x128 tile, BK=32, 256 thr / 4 waves, each wave 64x64 (4x4 MFMA tiles).
// Staged tiles use chunk-XOR swizzle (key = tile-local row & 3) applied on the
// GLOBAL source side (LDS side of global_load_lds must stay lane-linear).
template<int WRITE_F32>
__global__ __launch_bounds__(256) void gemm_bt(
    const unsigned short* __restrict__ A,
    const unsigned short* __restrict__ B,
    void* __restrict__ Cout, int M, int N, int K)
{
    __shared__ __attribute__((aligned(16))) unsigned short sA[128*32];
    __shared__ __attribute__((aligned(16))) unsigned short sB[128*32];
    const int tid  = threadIdx.x;
    const int lane = tid & 63;
    const int wv   = tid >> 6;
    const int wm   = (wv >> 1) * 64;
    const int wn   = (wv & 1) * 64;
    const int quad = lane >> 4;
    const int lr   = lane & 15;
    const int m0 = blockIdx.y * 128;
    const int n0 = blockIdx.x * 128;

    f32x4 acc[4][4] = {};
    const int nkt = K >> 5;
    for (int kt = 0; kt < nkt; ++kt) {
        const int k0 = kt << 5;
        #pragma unroll
        for (int p = 0; p < 2; ++p) {
            int e  = (p*256 + tid) * 8;
            int r  = e >> 5;                  // tile-local row 0..127
            int cc = (e & 31) >> 3;           // phys chunk 0..3
            int gc = (cc ^ (r & 3)) * 8;      // swizzled logical col
            async16(&A[(size_t)(m0 + r)*K + k0 + gc], &sA[e]);
            async16(&B[(size_t)(n0 + r)*K + k0 + gc], &sB[e]);
        }
        __syncthreads();
        s16x8 af[4], bf[4];
        #pragma unroll
        for (int i = 0; i < 4; ++i) {
            int row = wm + i*16 + lr;
            af[i] = *(const s16x8*)&sA[row*32 + ((quad ^ (row & 3)) * 8)];
        }
        #pragma unroll
        for (int j = 0; j < 4; ++j) {
            int row = wn + j*16 + lr;
            bf[j] = *(const s16x8*)&sB[row*32 + ((quad ^ (row & 3)) * 8)];
        }
        #pragma unroll
        for (int i = 0; i < 4; ++i)
            #pragma unroll
            for (int j = 0; j < 4; ++j)
                acc[i][j] = __builtin_amdgcn_mfma_f32_16x16x32_bf16(af[i], bf[j], acc[i][j], 0, 0, 0);
        __syncthreads();
    }
    // C/D layout: col = lane&15, row = (lane>>4)*4 + reg  (m89/m91 verified)
    #pragma unroll
    for (int i = 0; i < 4; ++i) {
        #pragma unroll
        for (int j = 0; j < 4; ++j) {
            #pragma unroll
            for (int r = 0; r < 4; ++r) {
                size_t row = (size_t)(m0 + wm + i*16 + quad*4 + r);
                size_t col = (size_t)(n0 + wn + j*16 + lr);
                float v = acc[i][j][r];
                if (WRITE_F32) ((float*)Cout)[row*(size_t)N + col] = v;
                else ((unsigned short*)Cout)[row*(size_t)N + col] = f32_to_bf16(v);
            }
        }
    }
}

// ---------------- RoPE + [B*S, NH*128] -> [B,NH,S,128] ----------------
template<int NHEADS>
__global__ __launch_bounds__(256) void rope_rearrange(
    const unsigned short* __restrict__ in, unsigned short* __restrict__ out)
{
    constexpr int LH = (NHEADS == 32) ? 5 : 3;
    int idx = blockIdx.x * 256 + threadIdx.x;
    int i  = idx & 63;
    int hh = (idx >> 6) & (NHEADS - 1);
    int s  = (idx >> (6 + LH)) & 2047;
    int b  = idx >> (17 + LH);
    const int D = NHEADS * 128;
    size_t inoff = (size_t)(b*2048 + s) * D + hh*128 + i;
    float x1 = bf16_to_f32(in[inoff]);
    float x2 = bf16_to_f32(in[inoff + 64]);
    float freq = expf((float)i * -0.14391156831212787f);  // ln(10000)/64
    float ang  = (float)s * freq;
    float sn, cs;
    sincosf(ang, &sn, &cs);
    size_t outoff = ((size_t)(b*NHEADS + hh) * 2048 + s) * 128 + i;
    out[outoff]      = f32_to_bf16(x1*cs - x2*sn);
    out[outoff + 64] = f32_to_bf16(x2*cs + x1*sn);
}

// ---------------- V: [B*S, G*128] -> [B,G,S,128] ----------------
__global__ __launch_bounds__(256) void rearrange_v(
    const unsigned short* __restrict__ in, unsigned short* __restrict__ out)
{
    int idx = blockIdx.x * 256 + threadIdx.x;   // B*S*8*16 = 524288
    int c = idx & 15;
    int g = (idx >> 4) & 7;
    int s = (idx >> 7) & 2047;
    int b = idx >> 18;
    size_t inoff  = ((size_t)(b*2048 + s)) * 1024 + g*128 + c*8;
    size_t outoff = ((size_t)((b*8 + g)*2048) + s) * 128 + c*8;
    *(uint4*)&out[outoff] = *(const uint4*)&in[inoff];
}

// ---------------- flash attention ----------------
// grid (S/64, B*H). Each WG: 64 q-rows; wave w owns rows q0+w*16..+15.
// KV tiles of 64, K async-staged (XOR swizzled), V staged transposed sVt[d][kv]
// (pad 72, chunk-XOR key (d>>3)&7). P roundtrips per-wave LDS (C->A layout).
__global__ __launch_bounds__(256) void flash_attn(
    const unsigned short* __restrict__ Q,   // [B,H,S,128]
    const unsigned short* __restrict__ K,   // [B,G,S,128]
    const unsigned short* __restrict__ V,   // [B,G,S,128]
    unsigned short* __restrict__ ctx)       // [B*S, H*128]
{
    __shared__ __attribute__((aligned(16))) unsigned short sK[64*128];
    __shared__ __attribute__((aligned(16))) unsigned short sVt[128*72];
    __shared__ __attribute__((aligned(16))) unsigned short sP[4*16*72];

    const int tid  = threadIdx.x;
    const int lane = tid & 63;
    const int w    = tid >> 6;
    const int quad = lane >> 4;
    const int lr   = lane & 15;
    const int qb = blockIdx.x;
    const int b  = blockIdx.y >> 5;
    const int h  = blockIdx.y & 31;
    const int g  = h >> 2;
    const int q0 = qb * 64;

    s16x8 qf[4];
    {
        const size_t qrow = ((size_t)(b*32 + h) * 2048 + q0 + w*16 + lr) * 128;
        #pragma unroll
        for (int kc = 0; kc < 4; ++kc)
            qf[kc] = *(const s16x8*)&Q[qrow + kc*32 + quad*8];
    }
    const size_t kvbase = (size_t)(b*8 + g) * 2048 * 128;

    float m_i[4], l_i[4];
    f32x4 o[8] = {};
    #pragma unroll
    for (int r = 0; r < 4; ++r) { m_i[r] = -1e30f; l_i[r] = 0.f; }
    unsigned short* sPw = &sP[w*16*72];

    for (int kt = 0; kt <= qb; ++kt) {
        const size_t kbase = kvbase + (size_t)kt*64*128;
        #pragma unroll
        for (int p = 0; p < 4; ++p) {                 // K: async, swizzled
            int e = (p*256 + tid) * 8;
            int r = e >> 7;
            int s = (e & 127) >> 3;
            int gsrc = (s ^ (r & 15)) * 8;
            async16(&K[kbase + (size_t)r*128 + gsrc], &sK[e]);
        }
        #pragma unroll
        for (int p = 0; p < 4; ++p) {                 // V: transpose into sVt
            int e = (p*256 + tid) * 8;
            int r = e >> 7;          // kv local
            int c = e & 127;         // d base (multiple of 8)
            s16x8 v = *(const s16x8*)&V[kbase + (size_t)r*128 + c];
            int pc = ((r >> 3) ^ ((c >> 3) & 7)) * 8 + (r & 7);
            #pragma unroll
            for (int jj = 0; jj < 8; ++jj)
                sVt[(c + jj)*72 + pc] = (unsigned short)v[jj];
        }
        __syncthreads();

        f32x4 sacc[4] = {};                           // scores = Q K^T
        #pragma unroll
        for (int ct = 0; ct < 4; ++ct) {
            int row = ct*16 + lr;
            int key = row & 15;
            #pragma unroll
            for (int kc = 0; kc < 4; ++kc) {
                int cc = kc*4 + quad;
                s16x8 kf = *(const s16x8*)&sK[row*128 + (cc ^ key)*8];
                sacc[ct] = __builtin_amdgcn_mfma_f32_16x16x32_bf16(qf[kc], kf, sacc[ct], 0, 0, 0);
            }
        }
        float p_[4][4];
        float alpha[4];
        #pragma unroll
        for (int r = 0; r < 4; ++r) {                 // online softmax
            const int qrow = q0 + w*16 + quad*4 + r;
            float vmax = -1e30f;
            #pragma unroll
            for (int ct = 0; ct < 4; ++ct) {
                int col = kt*64 + ct*16 + lr;
                float sv = sacc[ct][r] * 0.08838834764831845f;  // 1/sqrt(128)
                if (col > qrow) sv = -1e30f;
                p_[ct][r] = sv;
                vmax = fmaxf(vmax, sv);
            }
            vmax = fmaxf(vmax, __shfl_xor(vmax, 1));
            vmax = fmaxf(vmax, __shfl_xor(vmax, 2));
            vmax = fmaxf(vmax, __shfl_xor(vmax, 4));
            vmax = fmaxf(vmax, __shfl_xor(vmax, 8));
            float mnew = fmaxf(m_i[r], vmax);
            float a = __expf(m_i[r] - mnew);
            alpha[r] = a;
            m_i[r] = mnew;
            float rs = 0.f;
            #pragma unroll
            for (int ct = 0; ct < 4; ++ct) {
                float pv = __expf(p_[ct][r] - mnew);
                p_[ct][r] = pv;
                rs += pv;
            }
            rs += __shfl_xor(rs, 1);
            rs += __shfl_xor(rs, 2);
            rs += __shfl_xor(rs, 4);
            rs += __shfl_xor(rs, 8);
            l_i[r] = l_i[r] * a + rs;
        }
        #pragma unroll
        for (int t = 0; t < 8; ++t)
            #pragma unroll
            for (int r = 0; r < 4; ++r)
                o[t][r] = o[t][r] * alpha[r];
        #pragma unroll
        for (int ct = 0; ct < 4; ++ct)                // P: C-layout -> LDS
            #pragma unroll
            for (int r = 0; r < 4; ++r)
                sPw[(quad*4 + r)*72 + ct*16 + lr] = f32_to_bf16(p_[ct][r]);
        __builtin_amdgcn_wave_barrier();              // wave-local RAW; DS in-order
        #pragma unroll
        for (int t = 0; t < 8; ++t) {                 // O += P V
            const int d = t*16 + lr;
            const int key = (d >> 3) & 7;
            #pragma unroll
            for (int kc = 0; kc < 2; ++kc) {
                s16x8 pf = *(const s16x8*)&sPw[lr*72 + kc*32 + quad*8];
                int cc = kc*4 + quad;
                s16x8 vf = *(const s16x8*)&sVt[d*72 + (cc ^ key)*8];
                o[t] = __builtin_amdgcn_mfma_f32_16x16x32_bf16(pf, vf, o[t], 0, 0, 0);
            }
        }
        __syncthreads();
    }
    #pragma unroll
    for (int r = 0; r < 4; ++r) {
        float inv = 1.0f / l_i[r];
        int srow = q0 + w*16 + quad*4 + r;
        size_t obase = ((size_t)b*2048 + srow) * 4096 + h*128;
        #pragma unroll
        for (int t = 0; t < 8; ++t)
            ctx[obase + t*16 + lr] = f32_to_bf16(o[t][r] * inv);
    }
}

extern "C" void kernel_launch(void* const* d_in, const int* in_sizes, int n_in,
                              void* d_out, int out_size, void* d_ws, size_t ws_size,
                              hipStream_t stream)
{
    const float* x  = (const float*)d_in[0];
    const float* Wq = (const float*)d_in[1];
    const float* Wk = (const float*)d_in[2];
    const float* Wv = (const float*)d_in[3];
    const float* Wo = (const float*)d_in[4];
    float* out = (float*)d_out;
    char* ws = (char*)d_ws;

    // workspace layout (184,549,376 B total)
    unsigned short* xb   = (unsigned short*)(ws);              // 33.5 MB
    unsigned short* Wqb  = (unsigned short*)(ws + 33554432);   // 33.5 MB
    unsigned short* Wkb  = (unsigned short*)(ws + 67108864);   //  8.4 MB
    unsigned short* Wvb  = (unsigned short*)(ws + 75497472);   //  8.4 MB
    unsigned short* Wob  = (unsigned short*)(ws + 83886080);   // 33.5 MB
    unsigned short* Qlin = (unsigned short*)(ws + 117440512);  // 33.5 MB
    unsigned short* Klin = (unsigned short*)(ws + 150994944);  //  8.4 MB
    unsigned short* Vlin = (unsigned short*)(ws + 159383552);  //  8.4 MB
    unsigned short* Kr   = (unsigned short*)(ws + 167772160);  //  8.4 MB
    unsigned short* Vr   = (unsigned short*)(ws + 176160768);  //  8.4 MB
    unsigned short* Qr   = xb;    // alias: xb dead after QKV GEMMs
    unsigned short* ctxb = Qlin;  // alias: Qlin dead after rope

    cast_f32_bf16<<<16384, 256, 0, stream>>>(x,  xb,  4194304);
    cast_f32_bf16<<<16384, 256, 0, stream>>>(Wq, Wqb, 4194304);
    cast_f32_bf16<<<4096,  256, 0, stream>>>(Wk, Wkb, 1048576);
    cast_f32_bf16<<<4096,  256, 0, stream>>>(Wv, Wvb, 1048576);
    cast_f32_bf16<<<16384, 256, 0, stream>>>(Wo, Wob, 4194304);

    gemm_bt<0><<<dim3(32, 32), 256, 0, stream>>>(xb, Wqb, Qlin, 4096, 4096, 4096);
    gemm_bt<0><<<dim3(8, 32),  256, 0, stream>>>(xb, Wkb, Klin, 4096, 1024, 4096);
    gemm_bt<0><<<dim3(8, 32),  256, 0, stream>>>(xb, Wvb, Vlin, 4096, 1024, 4096);

    rope_rearrange<32><<<32768, 256, 0, stream>>>(Qlin, Qr);
    rope_rearrange<8><<<8192,   256, 0, stream>>>(Klin, Kr);
    rearrange_v<<<2048, 256, 0, stream>>>(Vlin, Vr);

    flash_attn<<<dim3(32, 64), 256, 0, stream>>>(Qr, Kr, Vr, ctxb);

    gemm_bt<1><<<dim3(32, 32), 256, 0, stream>>>(ctxb, Wob, out, 4096, 4096, 4096);
}

// Round 2
// 1099.810 us; speedup vs baseline: 1.1171x; 1.1171x over previous
//
#include <hip/hip_runtime.h>

// Problem constants: B=2, S=2048, D_IN=D_OUT=4096, H=32, G=8, HD=128, GS=4
// All matmuls are C[M,N] = A[M,K] @ B[N,K]^T ("gemm_bt", K contiguous in both).

typedef float f32x4 __attribute__((ext_vector_type(4)));
typedef short s16x8 __attribute__((ext_vector_type(8)));

__device__ __forceinline__ unsigned short f32_to_bf16(float f) {
    unsigned int u = __float_as_uint(f);
    u += 0x7fffu + ((u >> 16) & 1u);   // round-to-nearest-even
    return (unsigned short)(u >> 16);
}
__device__ __forceinline__ float bf16_to_f32(unsigned short h) {
    return __uint_as_float(((unsigned int)h) << 16);
}
// async global->LDS, 16B per lane. LDS dest is wave-uniform base + lane*16.
__device__ __forceinline__ void async16(const unsigned short* g, unsigned short* l) {
    __builtin_amdgcn_global_load_lds(
        (const __attribute__((address_space(1))) unsigned int*)g,
        (__attribute__((address_space(3))) unsigned int*)l, 16, 0, 0);
}

// ---------------- fp32 -> bf16 cast ----------------
__global__ __launch_bounds__(256) void cast_f32_bf16(
    const float* __restrict__ in, unsigned short* __restrict__ out, int n4)
{
    int idx = blockIdx.x * 256 + threadIdx.x;
    if (idx >= n4) return;
    float4 v = ((const float4*)in)[idx];
    ushort4 o;
    o.x = f32_to_bf16(v.x); o.y = f32_to_bf16(v.y);
    o.z = f32_to_bf16(v.z); o.w = f32_to_bf16(v.w);
    ((ushort4*)out)[idx] = o;
}

// ---------------- bf16 gemm_bt: C = A[M,K] * B[N,K]^T ----------------
// 128x128 tile, BK=32, 256 thr / 4 waves, each wave 64x64 (4x4 MFMA tiles).
template<int WRITE_F32>
__global__ __launch_bounds__(256) void gemm_bt(
    const unsigned short* __restrict__ A,
    const unsigned short* __restrict__ B,
    void* __restrict__ Cout, int M, int N, int K)
{
    __shared__ __attribute__((aligned(16))) unsigned short sA[128*32];
    __shared__ __attribute__((aligned(16))) unsigned short sB[128*32];
    const int tid  = threadIdx.x;
    const int lane = tid & 63;
    const int wv   = tid >> 6;
    const int wm   = (wv >> 1) * 64;
    const int wn   = (wv & 1) * 64;
    const int quad = lane >> 4;
    const int lr   = lane & 15;
    const int m0 = blockIdx.y * 128;
    const int n0 = blockIdx.x * 128;

    f32x4 acc[4][4] = {};
    const int nkt = K >> 5;
    for (int kt = 0; kt < nkt; ++kt) {
        const int k0 = kt << 5;
        #pragma unroll
        for (int p = 0; p < 2; ++p) {
            int e  = (p*256 + tid) * 8;
            int r  = e >> 5;                  // tile-local row 0..127
            int cc = (e & 31) >> 3;           // phys chunk 0..3
            int gc = (cc ^ (r & 3)) * 8;      // swizzled logical col
            async16(&A[(size_t)(m0 + r)*K + k0 + gc], &sA[e]);
            async16(&B[(size_t)(n0 + r)*K + k0 + gc], &sB[e]);
        }
        __syncthreads();
        s16x8 af[4], bf[4];
        #pragma unroll
        for (int i = 0; i < 4; ++i) {
            int row = wm + i*16 + lr;
            af[i] = *(const s16x8*)&sA[row*32 + ((quad ^ (row & 3)) * 8)];
        }
        #pragma unroll
        for (int j = 0; j < 4; ++j) {
            int row = wn + j*16 + lr;
            bf[j] = *(const s16x8*)&sB[row*32 + ((quad ^ (row & 3)) * 8)];
        }
        #pragma unroll
        for (int i = 0; i < 4; ++i)
            #pragma unroll
            for (int j = 0; j < 4; ++j)
                acc[i][j] = __builtin_amdgcn_mfma_f32_16x16x32_bf16(af[i], bf[j], acc[i][j], 0, 0, 0);
        __syncthreads();
    }
    // C/D layout: col = lane&15, row = (lane>>4)*4 + reg  (m89/m91 verified)
    #pragma unroll
    for (int i = 0; i < 4; ++i) {
        #pragma unroll
        for (int j = 0; j < 4; ++j) {
            #pragma unroll
            for (int r = 0; r < 4; ++r) {
                size_t row = (size_t)(m0 + wm + i*16 + quad*4 + r);
                size_t col = (size_t)(n0 + wn + j*16 + lr);
                float v = acc[i][j][r];
                if (WRITE_F32) ((float*)Cout)[row*(size_t)N + col] = v;
                else ((unsigned short*)Cout)[row*(size_t)N + col] = f32_to_bf16(v);
            }
        }
    }
}

// ---------------- RoPE + [B*S, rowstride] -> [B,NH,S,128] ----------------
template<int NHEADS>
__global__ __launch_bounds__(256) void rope_rearrange(
    const unsigned short* __restrict__ in, unsigned short* __restrict__ out,
    int rowstride)
{
    constexpr int LH = (NHEADS == 32) ? 5 : 3;
    int idx = blockIdx.x * 256 + threadIdx.x;
    int i  = idx & 63;
    int hh = (idx >> 6) & (NHEADS - 1);
    int s  = (idx >> (6 + LH)) & 2047;
    int b  = idx >> (17 + LH);
    size_t inoff = (size_t)(b*2048 + s) * rowstride + hh*128 + i;
    float x1 = bf16_to_f32(in[inoff]);
    float x2 = bf16_to_f32(in[inoff + 64]);
    float freq = expf((float)i * -0.14391156831212787f);  // ln(10000)/64
    float ang  = (float)s * freq;
    float sn, cs;
    sincosf(ang, &sn, &cs);
    size_t outoff = ((size_t)(b*NHEADS + hh) * 2048 + s) * 128 + i;
    out[outoff]      = f32_to_bf16(x1*cs - x2*sn);
    out[outoff + 64] = f32_to_bf16(x2*cs + x1*sn);
}

// ---------------- V: KVlin[B*S, 2048] (cols 1024+) -> Vt [B,G,128,2048] ----
// LDS tile transpose: per block one (b,g) x 128-s tile.
__global__ __launch_bounds__(256) void rearrange_vt(
    const unsigned short* __restrict__ in, unsigned short* __restrict__ out)
{
    __shared__ __attribute__((aligned(16))) unsigned short sS[128*136];
    const int tid = threadIdx.x;
    const int bg  = blockIdx.y;
    const int b   = bg >> 3, g = bg & 7;
    const int s0  = blockIdx.x * 128;
    // phase 1: load 128s x 128d coalesced, store to LDS [s][d] (pad 136)
    #pragma unroll
    for (int p = 0; p < 8; ++p) {
        int ce = p*256 + tid;          // chunk: s = ce>>4, dc = ce&15
        int s  = ce >> 4, dc = ce & 15;
        s16x8 v = *(const s16x8*)&in[(size_t)(b*2048 + s0 + s)*2048 + 1024 + g*128 + dc*8];
        *(s16x8*)&sS[s*136 + dc*8] = v;
    }
    __syncthreads();
    // phase 2: write out rows d, contiguous along s
    const int d    = tid & 127;
    const int half = tid >> 7;
    const size_t obase = ((size_t)(bg)*128 + d)*2048 + s0;
    #pragma unroll
    for (int i = 0; i < 8; ++i) {
        int sc = half*8 + i;
        s16x8 ov;
        #pragma unroll
        for (int j = 0; j < 8; ++j)
            ov[j] = (short)sS[(sc*8 + j)*136 + d];
        *(s16x8*)&out[obase + sc*8] = ov;
    }
}

// ---------------- flash attention ----------------
// grid (S/64, B*H), qb reversed (heavy blocks first). Each WG: 64 q-rows;
// wave w owns rows q0+w*16..+15. KV tiles of 64. K and Vt async-staged with
// global-side chunk-XOR swizzle. P roundtrips per-wave LDS (C->A layout).
__global__ __launch_bounds__(256) void flash_attn(
    const unsigned short* __restrict__ Q,    // [B,H,S,128]
    const unsigned short* __restrict__ K,    // [B,G,S,128]
    const unsigned short* __restrict__ Vt,   // [B,G,128,S]
    unsigned short* __restrict__ ctx)        // [B*S, H*128]
{
    __shared__ __attribute__((aligned(16))) unsigned short sK[64*128];
    __shared__ __attribute__((aligned(16))) unsigned short sVt[128*64];
    __shared__ __attribute__((aligned(16))) unsigned short sP[4*16*72];

    const int tid  = threadIdx.x;
    const int lane = tid & 63;
    const int w    = tid >> 6;
    const int quad = lane >> 4;
    const int lr   = lane & 15;
    const int qb = 31 - blockIdx.x;          // heavy (large qb) blocks first
    const int b  = blockIdx.y >> 5;
    const int h  = blockIdx.y & 31;
    const int g  = h >> 2;
    const int q0 = qb * 64;

    s16x8 qf[4];
    {
        const size_t qrow = ((size_t)(b*32 + h) * 2048 + q0 + w*16 + lr) * 128;
        #pragma unroll
        for (int kc = 0; kc < 4; ++kc)
            qf[kc] = *(const s16x8*)&Q[qrow + kc*32 + quad*8];
    }
    const size_t kvbase = (size_t)(b*8 + g) * 2048 * 128;
    const size_t vtbase = (size_t)(b*8 + g) * 128 * 2048;

    float m_i[4], l_i[4];
    f32x4 o[8] = {};
    #pragma unroll
    for (int r = 0; r < 4; ++r) { m_i[r] = -1e30f; l_i[r] = 0.f; }
    unsigned short* sPw = &sP[w*16*72];

    for (int kt = 0; kt <= qb; ++kt) {
        const size_t kbase = kvbase + (size_t)kt*64*128;
        #pragma unroll
        for (int p = 0; p < 4; ++p) {                 // K: async, swizzled
            int e = (p*256 + tid) * 8;
            int r = e >> 7;
            int s = (e & 127) >> 3;
            int gsrc = (s ^ (r & 15)) * 8;
            async16(&K[kbase + (size_t)r*128 + gsrc], &sK[e]);
        }
        #pragma unroll
        for (int p = 0; p < 4; ++p) {                 // Vt: async, swizzled
            int ce = p*256 + tid;                     // d = ce>>3, c = ce&7
            int d  = ce >> 3;
            int c  = ce & 7;
            int gc = (c ^ (d & 7)) * 8;
            async16(&Vt[vtbase + (size_t)d*2048 + kt*64 + gc], &sVt[ce*8]);
        }
        __syncthreads();

        f32x4 sacc[4] = {};                           // scores = Q K^T
        #pragma unroll
        for (int ct = 0; ct < 4; ++ct) {
            int row = ct*16 + lr;
            int key = row & 15;
            #pragma unroll
            for (int kc = 0; kc < 4; ++kc) {
                int cc = kc*4 + quad;
                s16x8 kf = *(const s16x8*)&sK[row*128 + ((cc ^ key)*8)];
                sacc[ct] = __builtin_amdgcn_mfma_f32_16x16x32_bf16(qf[kc], kf, sacc[ct], 0, 0, 0);
            }
        }
        float p_[4][4];
        float alpha[4];
        const bool diag = (kt == qb);
        #pragma unroll
        for (int r = 0; r < 4; ++r) {                 // online softmax
            const int qrow = q0 + w*16 + quad*4 + r;
            float vmax = -1e30f;
            #pragma unroll
            for (int ct = 0; ct < 4; ++ct) {
                float sv = sacc[ct][r] * 0.08838834764831845f;  // 1/sqrt(128)
                if (diag) {
                    int col = kt*64 + ct*16 + lr;
                    if (col > qrow) sv = -1e30f;
                }
                p_[ct][r] = sv;
                vmax = fmaxf(vmax, sv);
            }
            vmax = fmaxf(vmax, __shfl_xor(vmax, 1));
            vmax = fmaxf(vmax, __shfl_xor(vmax, 2));
            vmax = fmaxf(vmax, __shfl_xor(vmax, 4));
            vmax = fmaxf(vmax, __shfl_xor(vmax, 8));
            float mnew = fmaxf(m_i[r], vmax);
            float a = __expf(m_i[r] - mnew);
            alpha[r] = a;
            m_i[r] = mnew;
            float rs = 0.f;
            #pragma unroll
            for (int ct = 0; ct < 4; ++ct) {
                float pv = __expf(p_[ct][r] - mnew);
                p_[ct][r] = pv;
                rs += pv;
            }
            rs += __shfl_xor(rs, 1);
            rs += __shfl_xor(rs, 2);
            rs += __shfl_xor(rs, 4);
            rs += __shfl_xor(rs, 8);
            l_i[r] = l_i[r] * a + rs;
        }
        #pragma unroll
        for (int t = 0; t < 8; ++t)
            #pragma unroll
            for (int r = 0; r < 4; ++r)
                o[t][r] = o[t][r] * alpha[r];
        #pragma unroll
        for (int ct = 0; ct < 4; ++ct)                // P: C-layout -> LDS
            #pragma unroll
            for (int r = 0; r < 4; ++r)
                sPw[(quad*4 + r)*72 + ct*16 + lr] = f32_to_bf16(p_[ct][r]);
        __builtin_amdgcn_wave_barrier();              // wave-local RAW; DS in-order
        s16x8 pf[2];                                  // hoisted P fragments
        pf[0] = *(const s16x8*)&sPw[lr*72 + quad*8];
        pf[1] = *(const s16x8*)&sPw[lr*72 + 32 + quad*8];
        #pragma unroll
        for (int t = 0; t < 8; ++t) {                 // O += P V
            const int d = t*16 + lr;
            const int key = d & 7;
            #pragma unroll
            for (int kc = 0; kc < 2; ++kc) {
                int cc = kc*4 + quad;
                s16x8 vf = *(const s16x8*)&sVt[d*64 + ((cc ^ key)*8)];
                o[t] = __builtin_amdgcn_mfma_f32_16x16x32_bf16(pf[kc], vf, o[t], 0, 0, 0);
            }
        }
        __syncthreads();
    }
    #pragma unroll
    for (int r = 0; r < 4; ++r) {
        float inv = 1.0f / l_i[r];
        int srow = q0 + w*16 + quad*4 + r;
        size_t obase = ((size_t)b*2048 + srow) * 4096 + h*128;
        #pragma unroll
        for (int t = 0; t < 8; ++t)
            ctx[obase + t*16 + lr] = f32_to_bf16(o[t][r] * inv);
    }
}

extern "C" void kernel_launch(void* const* d_in, const int* in_sizes, int n_in,
                              void* d_out, int out_size, void* d_ws, size_t ws_size,
                              hipStream_t stream)
{
    const float* x  = (const float*)d_in[0];
    const float* Wq = (const float*)d_in[1];
    const float* Wk = (const float*)d_in[2];
    const float* Wv = (const float*)d_in[3];
    const float* Wo = (const float*)d_in[4];
    float* out = (float*)d_out;
    char* ws = (char*)d_ws;

    // workspace layout (184,549,376 B total)
    unsigned short* xb    = (unsigned short*)(ws);              // 33.5 MB
    unsigned short* Wqb   = (unsigned short*)(ws + 33554432);   // 33.5 MB
    unsigned short* Wkvb  = (unsigned short*)(ws + 67108864);   // 16.8 MB (K rows 0..1023, V rows 1024..2047)
    unsigned short* Wob   = (unsigned short*)(ws + 83886080);   // 33.5 MB
    unsigned short* Qlin  = (unsigned short*)(ws + 117440512);  // 33.5 MB
    unsigned short* KVlin = (unsigned short*)(ws + 150994944);  // 16.8 MB [B*S, 2048]
    unsigned short* Kr    = (unsigned short*)(ws + 167772160);  //  8.4 MB
    unsigned short* Vt    = (unsigned short*)(ws + 176160768);  //  8.4 MB [B,G,128,S]
    unsigned short* Qr    = xb;    // alias: xb dead after QKV GEMMs
    unsigned short* ctxb  = Qlin;  // alias: Qlin dead after rope

    cast_f32_bf16<<<16384, 256, 0, stream>>>(x,  xb,  4194304);
    cast_f32_bf16<<<16384, 256, 0, stream>>>(Wq, Wqb, 4194304);
    cast_f32_bf16<<<4096,  256, 0, stream>>>(Wk, Wkvb,           1048576);
    cast_f32_bf16<<<4096,  256, 0, stream>>>(Wv, Wkvb + 4194304, 1048576);
    cast_f32_bf16<<<16384, 256, 0, stream>>>(Wo, Wob, 4194304);

    gemm_bt<0><<<dim3(32, 32), 256, 0, stream>>>(xb, Wqb,  Qlin,  4096, 4096, 4096);
    gemm_bt<0><<<dim3(16, 32), 256, 0, stream>>>(xb, Wkvb, KVlin, 4096, 2048, 4096);

    rope_rearrange<32><<<32768, 256, 0, stream>>>(Qlin,  Qr, 4096);
    rope_rearrange<8><<<8192,   256, 0, stream>>>(KVlin, Kr, 2048);
    rearrange_vt<<<dim3(16, 16), 256, 0, stream>>>(KVlin, Vt);

    flash_attn<<<dim3(32, 64), 256, 0, stream>>>(Qr, Kr, Vt, ctxb);

    gemm_bt<1><<<dim3(32, 32), 256, 0, stream>>>(ctxb, Wob, out, 4096, 4096, 4096);
}

// Round 4
// 1091.900 us; speedup vs baseline: 1.1252x; 1.0072x over previous
//
#include <hip/hip_runtime.h>

// Problem constants: B=2, S=2048, D_IN=D_OUT=4096, H=32, G=8, HD=128, GS=4
// All matmuls are C[M,N] = A[M,K] @ B[N,K]^T ("gemm_bt", K contiguous in both).

typedef float f32x4 __attribute__((ext_vector_type(4)));
typedef short s16x8 __attribute__((ext_vector_type(8)));

__device__ __forceinline__ unsigned short f32_to_bf16(float f) {
    unsigned int u = __float_as_uint(f);
    u += 0x7fffu + ((u >> 16) & 1u);   // round-to-nearest-even
    return (unsigned short)(u >> 16);
}
__device__ __forceinline__ float bf16_to_f32(unsigned short h) {
    return __uint_as_float(((unsigned int)h) << 16);
}
// async global->LDS, 16B per lane. LDS dest is wave-uniform base + lane*16.
__device__ __forceinline__ void async16(const unsigned short* g, unsigned short* l) {
    __builtin_amdgcn_global_load_lds(
        (const __attribute__((address_space(1))) unsigned int*)g,
        (__attribute__((address_space(3))) unsigned int*)l, 16, 0, 0);
}

// ---------------- fp32 -> bf16 cast ----------------
__global__ __launch_bounds__(256) void cast_f32_bf16(
    const float* __restrict__ in, unsigned short* __restrict__ out, int n4)
{
    int idx = blockIdx.x * 256 + threadIdx.x;
    if (idx >= n4) return;
    float4 v = ((const float4*)in)[idx];
    ushort4 o;
    o.x = f32_to_bf16(v.x); o.y = f32_to_bf16(v.y);
    o.z = f32_to_bf16(v.z); o.w = f32_to_bf16(v.w);
    ((ushort4*)out)[idx] = o;
}

// ---------------- bf16 gemm_bt: C = A[M,K] * B[N,K]^T ----------------
// 128x128 tile, BK=32, 256 thr / 4 waves, each wave 64x64 (4x4 MFMA tiles).
template<int WRITE_F32>
__global__ __launch_bounds__(256) void gemm_bt(
    const unsigned short* __restrict__ A,
    const unsigned short* __restrict__ B,
    void* __restrict__ Cout, int M, int N, int K)
{
    __shared__ __attribute__((aligned(16))) unsigned short sA[128*32];
    __shared__ __attribute__((aligned(16))) unsigned short sB[128*32];
    const int tid  = threadIdx.x;
    const int lane = tid & 63;
    const int wv   = tid >> 6;
    const int wm   = (wv >> 1) * 64;
    const int wn   = (wv & 1) * 64;
    const int quad = lane >> 4;
    const int lr   = lane & 15;
    const int m0 = blockIdx.y * 128;
    const int n0 = blockIdx.x * 128;

    f32x4 acc[4][4] = {};
    const int nkt = K >> 5;
    for (int kt = 0; kt < nkt; ++kt) {
        const int k0 = kt << 5;
        #pragma unroll
        for (int p = 0; p < 2; ++p) {
            int e  = (p*256 + tid) * 8;
            int r  = e >> 5;                  // tile-local row 0..127
            int cc = (e & 31) >> 3;           // phys chunk 0..3
            int gc = (cc ^ (r & 3)) * 8;      // swizzled logical col
            async16(&A[(size_t)(m0 + r)*K + k0 + gc], &sA[e]);
            async16(&B[(size_t)(n0 + r)*K + k0 + gc], &sB[e]);
        }
        __syncthreads();
        s16x8 af[4], bf[4];
        #pragma unroll
        for (int i = 0; i < 4; ++i) {
            int row = wm + i*16 + lr;
            af[i] = *(const s16x8*)&sA[row*32 + ((quad ^ (row & 3)) * 8)];
        }
        #pragma unroll
        for (int j = 0; j < 4; ++j) {
            int row = wn + j*16 + lr;
            bf[j] = *(const s16x8*)&sB[row*32 + ((quad ^ (row & 3)) * 8)];
        }
        #pragma unroll
        for (int i = 0; i < 4; ++i)
            #pragma unroll
            for (int j = 0; j < 4; ++j)
                acc[i][j] = __builtin_amdgcn_mfma_f32_16x16x32_bf16(af[i], bf[j], acc[i][j], 0, 0, 0);
        __syncthreads();
    }
    // C/D layout: col = lane&15, row = (lane>>4)*4 + reg  (m89/m91 verified)
    #pragma unroll
    for (int i = 0; i < 4; ++i) {
        #pragma unroll
        for (int j = 0; j < 4; ++j) {
            #pragma unroll
            for (int r = 0; r < 4; ++r) {
                size_t row = (size_t)(m0 + wm + i*16 + quad*4 + r);
                size_t col = (size_t)(n0 + wn + j*16 + lr);
                float v = acc[i][j][r];
                if (WRITE_F32) ((float*)Cout)[row*(size_t)N + col] = v;
                else ((unsigned short*)Cout)[row*(size_t)N + col] = f32_to_bf16(v);
            }
        }
    }
}

// ---------------- RoPE + [B*S, rowstride] -> [B,NH,S,128] ----------------
template<int NHEADS>
__global__ __launch_bounds__(256) void rope_rearrange(
    const unsigned short* __restrict__ in, unsigned short* __restrict__ out,
    int rowstride)
{
    constexpr int LH = (NHEADS == 32) ? 5 : 3;
    int idx = blockIdx.x * 256 + threadIdx.x;
    int i  = idx & 63;
    int hh = (idx >> 6) & (NHEADS - 1);
    int s  = (idx >> (6 + LH)) & 2047;
    int b  = idx >> (17 + LH);
    size_t inoff = (size_t)(b*2048 + s) * rowstride + hh*128 + i;
    float x1 = bf16_to_f32(in[inoff]);
    float x2 = bf16_to_f32(in[inoff + 64]);
    float freq = expf((float)i * -0.14391156831212787f);  // ln(10000)/64
    float ang  = (float)s * freq;
    float sn, cs;
    sincosf(ang, &sn, &cs);
    size_t outoff = ((size_t)(b*NHEADS + hh) * 2048 + s) * 128 + i;
    out[outoff]      = f32_to_bf16(x1*cs - x2*sn);
    out[outoff + 64] = f32_to_bf16(x2*cs + x1*sn);
}

// ---------------- V: KVlin[B*S, 2048] (cols 1024+) -> Vt [B,G,128,2048] ----
// LDS tile transpose: per block one (b,g) x 128-s tile.
__global__ __launch_bounds__(256) void rearrange_vt(
    const unsigned short* __restrict__ in, unsigned short* __restrict__ out)
{
    __shared__ __attribute__((aligned(16))) unsigned short sS[128*136];
    const int tid = threadIdx.x;
    const int bg  = blockIdx.y;
    const int b   = bg >> 3, g = bg & 7;
    const int s0  = blockIdx.x * 128;
    // phase 1: load 128s x 128d coalesced, store to LDS [s][d] (pad 136)
    #pragma unroll
    for (int p = 0; p < 8; ++p) {
        int ce = p*256 + tid;          // chunk: s = ce>>4, dc = ce&15
        int s  = ce >> 4, dc = ce & 15;
        s16x8 v = *(const s16x8*)&in[(size_t)(b*2048 + s0 + s)*2048 + 1024 + g*128 + dc*8];
        *(s16x8*)&sS[s*136 + dc*8] = v;
    }
    __syncthreads();
    // phase 2: write out rows d, contiguous along s
    const int d    = tid & 127;
    const int half = tid >> 7;
    const size_t obase = ((size_t)(bg)*128 + d)*2048 + s0;
    #pragma unroll
    for (int i = 0; i < 8; ++i) {
        int sc = half*8 + i;
        s16x8 ov;
        #pragma unroll
        for (int j = 0; j < 8; ++j)
            ov[j] = (short)sS[(sc*8 + j)*136 + d];
        *(s16x8*)&out[obase + sc*8] = ov;
    }
}

// ---------------- flash attention (double-buffered, ones-rows rowsum) ------
// grid (S/64, B*H), qb reversed (heavy blocks first). Each WG: 64 q-rows;
// wave w owns rows q0+w*16..+15. KV tiles of 64. K and Vt async-staged into
// ping-pong LDS buffers (global-side chunk-XOR swizzle); one barrier/tile.
// Row-sum of P via MFMA against constant ALL-ONES rows 128..143 of sVt (t=8):
// every output column n reads Vt row 128+n = ones, so EVERY lane's o[8][r]
// holds the rowsum (R3 bug: only row 128 was ones -> lanes lr!=0 got 0 -> NaN).
__global__ __launch_bounds__(256) void flash_attn(
    const unsigned short* __restrict__ Q,    // [B,H,S,128]
    const unsigned short* __restrict__ K,    // [B,G,S,128]
    const unsigned short* __restrict__ Vt,   // [B,G,128,S]
    unsigned short* __restrict__ ctx)        // [B*S, H*128]
{
    __shared__ __attribute__((aligned(16))) unsigned short sK[2][64*128];   // 2x16KB
    __shared__ __attribute__((aligned(16))) unsigned short sVt[2][144*64];  // 2x18KB (rows 128..143 const ones)
    __shared__ __attribute__((aligned(16))) unsigned short sP[4*16*72];     // 9KB

    const int tid  = threadIdx.x;
    const int lane = tid & 63;
    const int w    = tid >> 6;
    const int quad = lane >> 4;
    const int lr   = lane & 15;
    const int qb = 31 - blockIdx.x;          // heavy (large qb) blocks first
    const int b  = blockIdx.y >> 5;
    const int h  = blockIdx.y & 31;
    const int g  = h >> 2;
    const int q0 = qb * 64;

    s16x8 qf[4];
    {
        const size_t qrow = ((size_t)(b*32 + h) * 2048 + q0 + w*16 + lr) * 128;
        #pragma unroll
        for (int kc = 0; kc < 4; ++kc)
            qf[kc] = *(const s16x8*)&Q[qrow + kc*32 + quad*8];
    }
    const size_t kvbase = (size_t)(b*8 + g) * 2048 * 128;
    const size_t vtbase = (size_t)(b*8 + g) * 128 * 2048;

    // constant ALL-ONES rows 128..143 of each sVt buffer (never restaged)
    for (int i = tid; i < 16*64; i += 256) {
        sVt[0][128*64 + i] = (unsigned short)0x3F80;
        sVt[1][128*64 + i] = (unsigned short)0x3F80;
    }

    auto stage = [&](int kt, int bi) {
        const size_t kbase = kvbase + (size_t)kt*64*128;
        #pragma unroll
        for (int p = 0; p < 4; ++p) {                 // K: async, swizzled
            int e = (p*256 + tid) * 8;
            int r = e >> 7;
            int s = (e & 127) >> 3;
            int gsrc = (s ^ (r & 15)) * 8;
            async16(&K[kbase + (size_t)r*128 + gsrc], &sK[bi][e]);
        }
        #pragma unroll
        for (int p = 0; p < 4; ++p) {                 // Vt: async, swizzled
            int ce = p*256 + tid;                     // d = ce>>3, c = ce&7
            int d  = ce >> 3;
            int c  = ce & 7;
            int gc = (c ^ (d & 7)) * 8;
            async16(&Vt[vtbase + (size_t)d*2048 + kt*64 + gc], &sVt[bi][ce*8]);
        }
    };

    float m_i[4];
    f32x4 o[9] = {};                                  // o[8] = running row-sum
    #pragma unroll
    for (int r = 0; r < 4; ++r) m_i[r] = -1e30f;
    unsigned short* sPw = &sP[w*16*72];
    // exp2 domain: score2 = (q.k) * (1/sqrt(128) * log2(e))
    const float scale2 = 0.12751646f;

    stage(0, 0);
    int buf = 0;
    for (int kt = 0; kt <= qb; ++kt) {
        __syncthreads();                              // drains buf loads; protects buf^1 WAR
        if (kt < qb) stage(kt + 1, buf ^ 1);

        f32x4 sacc[4] = {};                           // scores = Q K^T
        #pragma unroll
        for (int ct = 0; ct < 4; ++ct) {
            int row = ct*16 + lr;
            int key = row & 15;
            #pragma unroll
            for (int kc = 0; kc < 4; ++kc) {
                int cc = kc*4 + quad;
                s16x8 kf = *(const s16x8*)&sK[buf][row*128 + ((cc ^ key)*8)];
                sacc[ct] = __builtin_amdgcn_mfma_f32_16x16x32_bf16(qf[kc], kf, sacc[ct], 0, 0, 0);
            }
        }
        float p_[4][4];
        float alpha[4];
        const bool diag = (kt == qb);
        #pragma unroll
        for (int r = 0; r < 4; ++r) {                 // online softmax (exp2 domain)
            const int qrow = q0 + w*16 + quad*4 + r;
            float vmax = -1e30f;
            #pragma unroll
            for (int ct = 0; ct < 4; ++ct) {
                float sv = sacc[ct][r] * scale2;
                if (diag) {
                    int col = kt*64 + ct*16 + lr;
                    if (col > qrow) sv = -1e30f;
                }
                p_[ct][r] = sv;
                vmax = fmaxf(vmax, sv);
            }
            vmax = fmaxf(vmax, __shfl_xor(vmax, 1));
            vmax = fmaxf(vmax, __shfl_xor(vmax, 2));
            vmax = fmaxf(vmax, __shfl_xor(vmax, 4));
            vmax = fmaxf(vmax, __shfl_xor(vmax, 8));
            float mnew = fmaxf(m_i[r], vmax);
            alpha[r] = exp2f(m_i[r] - mnew);
            m_i[r] = mnew;
            #pragma unroll
            for (int ct = 0; ct < 4; ++ct)
                p_[ct][r] = exp2f(p_[ct][r] - mnew);
        }
        #pragma unroll
        for (int t = 0; t < 9; ++t)
            #pragma unroll
            for (int r = 0; r < 4; ++r)
                o[t][r] = o[t][r] * alpha[r];
        #pragma unroll
        for (int ct = 0; ct < 4; ++ct)                // P: C-layout -> LDS
            #pragma unroll
            for (int r = 0; r < 4; ++r)
                sPw[(quad*4 + r)*72 + ct*16 + lr] = f32_to_bf16(p_[ct][r]);
        __builtin_amdgcn_wave_barrier();              // wave-local RAW; DS in-order
        s16x8 pf[2];                                  // hoisted P fragments
        pf[0] = *(const s16x8*)&sPw[lr*72 + quad*8];
        pf[1] = *(const s16x8*)&sPw[lr*72 + 32 + quad*8];
        #pragma unroll
        for (int t = 0; t < 9; ++t) {                 // O += P V (t=8: row-sums)
            const int d = t*16 + lr;
            const int key = d & 7;
            #pragma unroll
            for (int kc = 0; kc < 2; ++kc) {
                int cc = kc*4 + quad;
                s16x8 vf = *(const s16x8*)&sVt[buf][d*64 + ((cc ^ key)*8)];
                o[t] = __builtin_amdgcn_mfma_f32_16x16x32_bf16(pf[kc], vf, o[t], 0, 0, 0);
            }
        }
        buf ^= 1;
    }
    #pragma unroll
    for (int r = 0; r < 4; ++r) {
        float inv = 1.0f / o[8][r];                   // l_i from ones-rows MFMA
        int srow = q0 + w*16 + quad*4 + r;
        size_t obase = ((size_t)b*2048 + srow) * 4096 + h*128;
        #pragma unroll
        for (int t = 0; t < 8; ++t)
            ctx[obase + t*16 + lr] = f32_to_bf16(o[t][r] * inv);
    }
}

extern "C" void kernel_launch(void* const* d_in, const int* in_sizes, int n_in,
                              void* d_out, int out_size, void* d_ws, size_t ws_size,
                              hipStream_t stream)
{
    const float* x  = (const float*)d_in[0];
    const float* Wq = (const float*)d_in[1];
    const float* Wk = (const float*)d_in[2];
    const float* Wv = (const float*)d_in[3];
    const float* Wo = (const float*)d_in[4];
    float* out = (float*)d_out;
    char* ws = (char*)d_ws;

    // workspace layout (184,549,376 B total)
    unsigned short* xb    = (unsigned short*)(ws);              // 33.5 MB
    unsigned short* Wqb   = (unsigned short*)(ws + 33554432);   // 33.5 MB
    unsigned short* Wkvb  = (unsigned short*)(ws + 67108864);   // 16.8 MB (K rows 0..1023, V rows 1024..2047)
    unsigned short* Wob   = (unsigned short*)(ws + 83886080);   // 33.5 MB
    unsigned short* Qlin  = (unsigned short*)(ws + 117440512);  // 33.5 MB
    unsigned short* KVlin = (unsigned short*)(ws + 150994944);  // 16.8 MB [B*S, 2048]
    unsigned short* Kr    = (unsigned short*)(ws + 167772160);  //  8.4 MB
    unsigned short* Vt    = (unsigned short*)(ws + 176160768);  //  8.4 MB [B,G,128,S]
    unsigned short* Qr    = xb;    // alias: xb dead after QKV GEMMs
    unsigned short* ctxb  = Qlin;  // alias: Qlin dead after rope

    cast_f32_bf16<<<16384, 256, 0, stream>>>(x,  xb,  4194304);
    cast_f32_bf16<<<16384, 256, 0, stream>>>(Wq, Wqb, 4194304);
    cast_f32_bf16<<<4096,  256, 0, stream>>>(Wk, Wkvb,           1048576);
    cast_f32_bf16<<<4096,  256, 0, stream>>>(Wv, Wkvb + 4194304, 1048576);
    cast_f32_bf16<<<16384, 256, 0, stream>>>(Wo, Wob, 4194304);

    gemm_bt<0><<<dim3(32, 32), 256, 0, stream>>>(xb, Wqb,  Qlin,  4096, 4096, 4096);
    gemm_bt<0><<<dim3(16, 32), 256, 0, stream>>>(xb, Wkvb, KVlin, 4096, 2048, 4096);

    rope_rearrange<32><<<32768, 256, 0, stream>>>(Qlin,  Qr, 4096);
    rope_rearrange<8><<<8192,   256, 0, stream>>>(KVlin, Kr, 2048);
    rearrange_vt<<<dim3(16, 16), 256, 0, stream>>>(KVlin, Vt);

    flash_attn<<<dim3(32, 64), 256, 0, stream>>>(Qr, Kr, Vt, ctxb);

    gemm_bt<1><<<dim3(32, 32), 256, 0, stream>>>(ctxb, Wob, out, 4096, 4096, 4096);
}

// Round 5
// 1076.130 us; speedup vs baseline: 1.1417x; 1.0147x over previous
//
#include <hip/hip_runtime.h>

// Problem constants: B=2, S=2048, D_IN=D_OUT=4096, H=32, G=8, HD=128, GS=4
// All matmuls are C[M,N] = A[M,K] @ B[N,K]^T ("gemm_bt", K contiguous in both).

typedef float f32x4 __attribute__((ext_vector_type(4)));
typedef short s16x8 __attribute__((ext_vector_type(8)));
typedef short s16x4 __attribute__((ext_vector_type(4)));

__device__ __forceinline__ unsigned short f32_to_bf16(float f) {
    unsigned int u = __float_as_uint(f);
    u += 0x7fffu + ((u >> 16) & 1u);   // round-to-nearest-even
    return (unsigned short)(u >> 16);
}
__device__ __forceinline__ float bf16_to_f32(unsigned short h) {
    return __uint_as_float(((unsigned int)h) << 16);
}
// async global->LDS, 16B per lane. LDS dest is wave-uniform base + lane*16.
__device__ __forceinline__ void async16(const unsigned short* g, unsigned short* l) {
    __builtin_amdgcn_global_load_lds(
        (const __attribute__((address_space(1))) unsigned int*)g,
        (__attribute__((address_space(3))) unsigned int*)l, 16, 0, 0);
}

// ---------------- fp32 -> bf16 cast ----------------
__global__ __launch_bounds__(256) void cast_f32_bf16(
    const float* __restrict__ in, unsigned short* __restrict__ out, int n4)
{
    int idx = blockIdx.x * 256 + threadIdx.x;
    if (idx >= n4) return;
    float4 v = ((const float4*)in)[idx];
    ushort4 o;
    o.x = f32_to_bf16(v.x); o.y = f32_to_bf16(v.y);
    o.z = f32_to_bf16(v.z); o.w = f32_to_bf16(v.w);
    ((ushort4*)out)[idx] = o;
}

// ---------------- bf16 gemm_bt: C = A[M,K] * B[N,K]^T ----------------
// 128x128 tile, BK=32, 256 thr / 4 waves, each wave 64x64 (4x4 MFMA tiles).
template<int WRITE_F32>
__global__ __launch_bounds__(256) void gemm_bt(
    const unsigned short* __restrict__ A,
    const unsigned short* __restrict__ B,
    void* __restrict__ Cout, int M, int N, int K)
{
    __shared__ __attribute__((aligned(16))) unsigned short sA[128*32];
    __shared__ __attribute__((aligned(16))) unsigned short sB[128*32];
    const int tid  = threadIdx.x;
    const int lane = tid & 63;
    const int wv   = tid >> 6;
    const int wm   = (wv >> 1) * 64;
    const int wn   = (wv & 1) * 64;
    const int quad = lane >> 4;
    const int lr   = lane & 15;
    const int m0 = blockIdx.y * 128;
    const int n0 = blockIdx.x * 128;

    f32x4 acc[4][4] = {};
    const int nkt = K >> 5;
    for (int kt = 0; kt < nkt; ++kt) {
        const int k0 = kt << 5;
        #pragma unroll
        for (int p = 0; p < 2; ++p) {
            int e  = (p*256 + tid) * 8;
            int r  = e >> 5;                  // tile-local row 0..127
            int cc = (e & 31) >> 3;           // phys chunk 0..3
            int gc = (cc ^ (r & 3)) * 8;      // swizzled logical col
            async16(&A[(size_t)(m0 + r)*K + k0 + gc], &sA[e]);
            async16(&B[(size_t)(n0 + r)*K + k0 + gc], &sB[e]);
        }
        __syncthreads();
        s16x8 af[4], bf[4];
        #pragma unroll
        for (int i = 0; i < 4; ++i) {
            int row = wm + i*16 + lr;
            af[i] = *(const s16x8*)&sA[row*32 + ((quad ^ (row & 3)) * 8)];
        }
        #pragma unroll
        for (int j = 0; j < 4; ++j) {
            int row = wn + j*16 + lr;
            bf[j] = *(const s16x8*)&sB[row*32 + ((quad ^ (row & 3)) * 8)];
        }
        #pragma unroll
        for (int i = 0; i < 4; ++i)
            #pragma unroll
            for (int j = 0; j < 4; ++j)
                acc[i][j] = __builtin_amdgcn_mfma_f32_16x16x32_bf16(af[i], bf[j], acc[i][j], 0, 0, 0);
        __syncthreads();
    }
    // C/D layout: col = lane&15, row = (lane>>4)*4 + reg  (m89/m91 verified)
    #pragma unroll
    for (int i = 0; i < 4; ++i) {
        #pragma unroll
        for (int j = 0; j < 4; ++j) {
            #pragma unroll
            for (int r = 0; r < 4; ++r) {
                size_t row = (size_t)(m0 + wm + i*16 + quad*4 + r);
                size_t col = (size_t)(n0 + wn + j*16 + lr);
                float v = acc[i][j][r];
                if (WRITE_F32) ((float*)Cout)[row*(size_t)N + col] = v;
                else ((unsigned short*)Cout)[row*(size_t)N + col] = f32_to_bf16(v);
            }
        }
    }
}

// ---------------- RoPE + [B*S, rowstride] -> [B,NH,S,128] ----------------
template<int NHEADS>
__global__ __launch_bounds__(256) void rope_rearrange(
    const unsigned short* __restrict__ in, unsigned short* __restrict__ out,
    int rowstride)
{
    constexpr int LH = (NHEADS == 32) ? 5 : 3;
    int idx = blockIdx.x * 256 + threadIdx.x;
    int i  = idx & 63;
    int hh = (idx >> 6) & (NHEADS - 1);
    int s  = (idx >> (6 + LH)) & 2047;
    int b  = idx >> (17 + LH);
    size_t inoff = (size_t)(b*2048 + s) * rowstride + hh*128 + i;
    float x1 = bf16_to_f32(in[inoff]);
    float x2 = bf16_to_f32(in[inoff + 64]);
    float freq = expf((float)i * -0.14391156831212787f);  // ln(10000)/64
    float ang  = (float)s * freq;
    float sn, cs;
    sincosf(ang, &sn, &cs);
    size_t outoff = ((size_t)(b*NHEADS + hh) * 2048 + s) * 128 + i;
    out[outoff]      = f32_to_bf16(x1*cs - x2*sn);
    out[outoff + 64] = f32_to_bf16(x2*cs + x1*sn);
}

// ---------------- V: KVlin[B*S, 2048] (cols 1024+) -> Vt [B,G,128,2048] ----
// LDS tile transpose: per block one (b,g) x 128-s tile.
__global__ __launch_bounds__(256) void rearrange_vt(
    const unsigned short* __restrict__ in, unsigned short* __restrict__ out)
{
    __shared__ __attribute__((aligned(16))) unsigned short sS[128*136];
    const int tid = threadIdx.x;
    const int bg  = blockIdx.y;
    const int b   = bg >> 3, g = bg & 7;
    const int s0  = blockIdx.x * 128;
    // phase 1: load 128s x 128d coalesced, store to LDS [s][d] (pad 136)
    #pragma unroll
    for (int p = 0; p < 8; ++p) {
        int ce = p*256 + tid;          // chunk: s = ce>>4, dc = ce&15
        int s  = ce >> 4, dc = ce & 15;
        s16x8 v = *(const s16x8*)&in[(size_t)(b*2048 + s0 + s)*2048 + 1024 + g*128 + dc*8];
        *(s16x8*)&sS[s*136 + dc*8] = v;
    }
    __syncthreads();
    // phase 2: write out rows d, contiguous along s
    const int d    = tid & 127;
    const int half = tid >> 7;
    const size_t obase = ((size_t)(bg)*128 + d)*2048 + s0;
    #pragma unroll
    for (int i = 0; i < 8; ++i) {
        int sc = half*8 + i;
        s16x8 ov;
        #pragma unroll
        for (int j = 0; j < 8; ++j)
            ov[j] = (short)sS[(sc*8 + j)*136 + d];
        *(s16x8*)&out[obase + sc*8] = ov;
    }
}

// ---------------- flash attention v2 (S^T trick, 32 q-rows/wave) ----------
// grid (S/128, B*H), qbi reversed. WG = 128 q-rows, wave w owns 32 (2 sub-
// tiles of 16). KV tiles of 64, K+Vt async double-buffered (XOR swizzle).
// QK^T computed TRANSPOSED (A=K, B=Q): S^T C-layout col=lane&15=q,
// row=quad*4+r=kv. That register layout IS the A-frag k=quad*4+j of a K=16
// PV MFMA, emulated as verified 16x16x32 MFMA with k-slots 4..7 zeroed on
// both A and B. No P LDS roundtrip; softmax reduces in-lane + shfl 16/32.
__global__ __launch_bounds__(256, 2) void flash_attn(
    const unsigned short* __restrict__ Q,    // [B,H,S,128]
    const unsigned short* __restrict__ K,    // [B,G,S,128]
    const unsigned short* __restrict__ Vt,   // [B,G,128,S]
    unsigned short* __restrict__ ctx)        // [B*S, H*128]
{
    __shared__ __attribute__((aligned(16))) unsigned short sK[2][64*128];   // 2x16KB
    __shared__ __attribute__((aligned(16))) unsigned short sVt[2][128*64];  // 2x16KB

    const int tid  = threadIdx.x;
    const int lane = tid & 63;
    const int w    = tid >> 6;
    const int quad = lane >> 4;
    const int lr   = lane & 15;
    const int qbi = 15 - blockIdx.x;         // heavy blocks first
    const int b  = blockIdx.y >> 5;
    const int h  = blockIdx.y & 31;
    const int g  = h >> 2;
    const int q0 = qbi * 128;
    const int qw0 = q0 + w * 32;             // wave's first q-row
    const int KT = 2*qbi + 2;                // kv tiles needed by this WG

    s16x8 qf[2][4];                          // B-frag: n=q=lane&15, k=d=quad*8+j
    #pragma unroll
    for (int qt = 0; qt < 2; ++qt) {
        const size_t qrow = ((size_t)(b*32 + h) * 2048 + qw0 + qt*16 + lr) * 128;
        #pragma unroll
        for (int kc = 0; kc < 4; ++kc)
            qf[qt][kc] = *(const s16x8*)&Q[qrow + kc*32 + quad*8];
    }
    const size_t kvbase = (size_t)(b*8 + g) * 2048 * 128;
    const size_t vtbase = (size_t)(b*8 + g) * 128 * 2048;

    auto stage = [&](int kt, int bi) {
        const size_t kbase = kvbase + (size_t)kt*64*128;
        #pragma unroll
        for (int p = 0; p < 4; ++p) {                 // K: async, swizzled
            int e = (p*256 + tid) * 8;
            int r = e >> 7;
            int s = (e & 127) >> 3;
            int gsrc = (s ^ (r & 15)) * 8;
            async16(&K[kbase + (size_t)r*128 + gsrc], &sK[bi][e]);
        }
        #pragma unroll
        for (int p = 0; p < 4; ++p) {                 // Vt: async, swizzled
            int ce = p*256 + tid;                     // d = ce>>3, c = ce&7
            int d  = ce >> 3;
            int c  = ce & 7;
            int gc = (c ^ (d & 7)) * 8;
            async16(&Vt[vtbase + (size_t)d*2048 + kt*64 + gc], &sVt[bi][ce*8]);
        }
    };

    float m_[2] = {-1e30f, -1e30f};
    float l_[2] = {0.f, 0.f};
    f32x4 o[2][8] = {};
    const float scale2 = 0.12751646f;        // 1/sqrt(128) * log2(e)

    stage(0, 0);
    int buf = 0;
    for (int kt = 0; kt < KT; ++kt) {
        __syncthreads();                     // drains buf loads; WAR on buf^1
        if (kt + 1 < KT) stage(kt + 1, buf ^ 1);

        if (kt*64 <= qw0 + 31) {             // wave has visible kv (uniform)
            const bool v0 = (kt*64 <= qw0 + 15);   // qt=0 sub-tile visible
            f32x4 sacc[2][4] = {};           // S^T tiles: [qt][ct]
            #pragma unroll
            for (int ct = 0; ct < 4; ++ct) {
                int row = ct*16 + lr;        // kv-local (A m-index)
                int key = row & 15;
                #pragma unroll
                for (int kc = 0; kc < 4; ++kc) {
                    s16x8 kf = *(const s16x8*)&sK[buf][row*128 + (((kc*4 + quad) ^ key)*8)];
                    if (v0) sacc[0][ct] = __builtin_amdgcn_mfma_f32_16x16x32_bf16(kf, qf[0][kc], sacc[0][ct], 0, 0, 0);
                    sacc[1][ct] = __builtin_amdgcn_mfma_f32_16x16x32_bf16(kf, qf[1][kc], sacc[1][ct], 0, 0, 0);
                }
            }
            s16x8 pa[2][4];                  // P as zero-padded K=32 A-frags
            #pragma unroll
            for (int qt = 0; qt < 2; ++qt) {
                if (qt == 0 && !v0) continue;
                const int qbase = qw0 + qt*16;
                const bool anymask = (kt*64 + 63) > qbase;
                const int qg = qbase + lr;   // this lane's q-row
                float p[4][4];
                float vmax = -1e30f;
                #pragma unroll
                for (int ct = 0; ct < 4; ++ct)
                    #pragma unroll
                    for (int r = 0; r < 4; ++r) {
                        float sv = sacc[qt][ct][r] * scale2;
                        if (anymask) {
                            int kv = kt*64 + ct*16 + quad*4 + r;
                            if (kv > qg) sv = -1e30f;
                        }
                        p[ct][r] = sv;
                        vmax = fmaxf(vmax, sv);
                    }
                vmax = fmaxf(vmax, __shfl_xor(vmax, 16));
                vmax = fmaxf(vmax, __shfl_xor(vmax, 32));
                float mnew = fmaxf(m_[qt], vmax);
                float alpha = exp2f(m_[qt] - mnew);
                m_[qt] = mnew;
                float rs = 0.f;
                #pragma unroll
                for (int ct = 0; ct < 4; ++ct)
                    #pragma unroll
                    for (int r = 0; r < 4; ++r) {
                        float pv = exp2f(p[ct][r] - mnew);
                        p[ct][r] = pv;
                        rs += pv;
                    }
                rs += __shfl_xor(rs, 16);
                rs += __shfl_xor(rs, 32);
                l_[qt] = l_[qt] * alpha + rs;
                #pragma unroll
                for (int ct = 0; ct < 4; ++ct) {
                    s16x8 a;
                    a[0] = (short)f32_to_bf16(p[ct][0]);
                    a[1] = (short)f32_to_bf16(p[ct][1]);
                    a[2] = (short)f32_to_bf16(p[ct][2]);
                    a[3] = (short)f32_to_bf16(p[ct][3]);
                    a[4] = 0; a[5] = 0; a[6] = 0; a[7] = 0;
                    pa[qt][ct] = a;
                }
                f32x4 av;                    // alpha per O-row q=quad*4+r
                #pragma unroll
                for (int r = 0; r < 4; ++r)
                    av[r] = __shfl(alpha, quad*4 + r);
                #pragma unroll
                for (int t = 0; t < 8; ++t)
                    o[qt][t] = o[qt][t] * av;
            }
            #pragma unroll
            for (int t = 0; t < 8; ++t) {    // O += P V
                const int d = t*16 + lr;
                const int dk = d & 7;
                #pragma unroll
                for (int ct = 0; ct < 4; ++ct) {
                    int c8  = 2*ct + (quad >> 1);
                    int off = ((c8 ^ dk) * 8) + ((quad & 1) * 4);
                    s16x4 v4 = *(const s16x4*)&sVt[buf][d*64 + off];
                    s16x8 v8;
                    v8[0] = v4[0]; v8[1] = v4[1]; v8[2] = v4[2]; v8[3] = v4[3];
                    v8[4] = 0; v8[5] = 0; v8[6] = 0; v8[7] = 0;
                    if (v0) o[0][t] = __builtin_amdgcn_mfma_f32_16x16x32_bf16(pa[0][ct], v8, o[0][t], 0, 0, 0);
                    o[1][t] = __builtin_amdgcn_mfma_f32_16x16x32_bf16(pa[1][ct], v8, o[1][t], 0, 0, 0);
                }
            }
        }
        buf ^= 1;
    }
    #pragma unroll
    for (int qt = 0; qt < 2; ++qt) {
        f32x4 lv;
        #pragma unroll
        for (int r = 0; r < 4; ++r)
            lv[r] = __shfl(l_[qt], quad*4 + r);
        #pragma unroll
        for (int r = 0; r < 4; ++r) {
            float inv = 1.0f / lv[r];
            int q = q0 + w*32 + qt*16 + quad*4 + r;
            size_t obase = ((size_t)b*2048 + q) * 4096 + h*128;
            #pragma unroll
            for (int t = 0; t < 8; ++t)
                ctx[obase + t*16 + lr] = f32_to_bf16(o[qt][t][r] * inv);
        }
    }
}

extern "C" void kernel_launch(void* const* d_in, const int* in_sizes, int n_in,
                              void* d_out, int out_size, void* d_ws, size_t ws_size,
                              hipStream_t stream)
{
    const float* x  = (const float*)d_in[0];
    const float* Wq = (const float*)d_in[1];
    const float* Wk = (const float*)d_in[2];
    const float* Wv = (const float*)d_in[3];
    const float* Wo = (const float*)d_in[4];
    float* out = (float*)d_out;
    char* ws = (char*)d_ws;

    // workspace layout (184,549,376 B total)
    unsigned short* xb    = (unsigned short*)(ws);              // 33.5 MB
    unsigned short* Wqb   = (unsigned short*)(ws + 33554432);   // 33.5 MB
    unsigned short* Wkvb  = (unsigned short*)(ws + 67108864);   // 16.8 MB (K rows 0..1023, V rows 1024..2047)
    unsigned short* Wob   = (unsigned short*)(ws + 83886080);   // 33.5 MB
    unsigned short* Qlin  = (unsigned short*)(ws + 117440512);  // 33.5 MB
    unsigned short* KVlin = (unsigned short*)(ws + 150994944);  // 16.8 MB [B*S, 2048]
    unsigned short* Kr    = (unsigned short*)(ws + 167772160);  //  8.4 MB
    unsigned short* Vt    = (unsigned short*)(ws + 176160768);  //  8.4 MB [B,G,128,S]
    unsigned short* Qr    = xb;    // alias: xb dead after QKV GEMMs
    unsigned short* ctxb  = Qlin;  // alias: Qlin dead after rope

    cast_f32_bf16<<<16384, 256, 0, stream>>>(x,  xb,  4194304);
    cast_f32_bf16<<<16384, 256, 0, stream>>>(Wq, Wqb, 4194304);
    cast_f32_bf16<<<4096,  256, 0, stream>>>(Wk, Wkvb,           1048576);
    cast_f32_bf16<<<4096,  256, 0, stream>>>(Wv, Wkvb + 4194304, 1048576);
    cast_f32_bf16<<<16384, 256, 0, stream>>>(Wo, Wob, 4194304);

    gemm_bt<0><<<dim3(32, 32), 256, 0, stream>>>(xb, Wqb,  Qlin,  4096, 4096, 4096);
    gemm_bt<0><<<dim3(16, 32), 256, 0, stream>>>(xb, Wkvb, KVlin, 4096, 2048, 4096);

    rope_rearrange<32><<<32768, 256, 0, stream>>>(Qlin,  Qr, 4096);
    rope_rearrange<8><<<8192,   256, 0, stream>>>(KVlin, Kr, 2048);
    rearrange_vt<<<dim3(16, 16), 256, 0, stream>>>(KVlin, Vt);

    flash_attn<<<dim3(16, 64), 256, 0, stream>>>(Qr, Kr, Vt, ctxb);

    gemm_bt<1><<<dim3(32, 32), 256, 0, stream>>>(ctxb, Wob, out, 4096, 4096, 4096);
}